// Round 3
// baseline (96.178 us; speedup 1.0000x reference)
//
#include <hip/hip_runtime.h>
#include <hip/hip_bf16.h>

#define NN 512
#define PITCH 34   // pitch≡2 (mod 8): ty/tx fragment groups land 8 banks apart -> 2-way (free)

// ---------------- Kernel 1: S = P*P^T ----------------------------------------
// 32x32 tile, 64 threads (ONE wave), 4x4 register micro-tile, row-major LDS,
// k-vectorized float4 fragments read as float2 pairs (8B-aligned, conflict-free).
// Register-prefetch double buffer; barriers are single-wave (near-free).
__global__ __launch_bounds__(64) void sap_gemm(const float* __restrict__ P,
                                               float* __restrict__ S,
                                               float* __restrict__ g_acc,
                                               unsigned int* __restrict__ g_cnt) {
    __shared__ float As[2][32][PITCH];
    __shared__ float Bs[2][32][PITCH];
    const int t  = threadIdx.x;
    const int tx = t & 7, ty = t >> 3;
    const int i0 = blockIdx.y * 32, j0 = blockIdx.x * 32;

    if (blockIdx.x == 0 && blockIdx.y == 0 && t == 0) { *g_acc = 0.f; *g_cnt = 0u; }

    // staging: thread t owns float4 #(t + 64p), p=0..3: row=(t>>3)+8p, col=(t&7)*4
    const int srow = t >> 3;
    const int scol = (t & 7) * 4;

    float4 a_reg[4], b_reg[4];
#pragma unroll
    for (int p = 0; p < 4; p++) {
        a_reg[p] = *(const float4*)&P[(i0 + srow + 8 * p) * NN + scol];
        b_reg[p] = *(const float4*)&P[(j0 + srow + 8 * p) * NN + scol];
    }
#pragma unroll
    for (int p = 0; p < 4; p++) {
        *(float2*)&As[0][srow + 8 * p][scol]     = make_float2(a_reg[p].x, a_reg[p].y);
        *(float2*)&As[0][srow + 8 * p][scol + 2] = make_float2(a_reg[p].z, a_reg[p].w);
        *(float2*)&Bs[0][srow + 8 * p][scol]     = make_float2(b_reg[p].x, b_reg[p].y);
        *(float2*)&Bs[0][srow + 8 * p][scol + 2] = make_float2(b_reg[p].z, b_reg[p].w);
    }

    float acc[4][4] = {};

    for (int c = 0; c < 16; c++) {
        const int cur = c & 1;
        if (c < 15) {                       // prefetch next chunk into registers
            const int kt = (c + 1) * 32;
#pragma unroll
            for (int p = 0; p < 4; p++) {
                a_reg[p] = *(const float4*)&P[(i0 + srow + 8 * p) * NN + kt + scol];
                b_reg[p] = *(const float4*)&P[(j0 + srow + 8 * p) * NN + kt + scol];
            }
        }
        __syncthreads();                    // stage->compute ordering (1 wave: cheap)
#pragma unroll
        for (int kk = 0; kk < 32; kk += 4) {
            float4 ar[4], bc[4];
#pragma unroll
            for (int r = 0; r < 4; r++) {
                float2 alo = *(const float2*)&As[cur][4 * ty + r][kk];
                float2 ahi = *(const float2*)&As[cur][4 * ty + r][kk + 2];
                float2 blo = *(const float2*)&Bs[cur][4 * tx + r][kk];
                float2 bhi = *(const float2*)&Bs[cur][4 * tx + r][kk + 2];
                ar[r] = make_float4(alo.x, alo.y, ahi.x, ahi.y);
                bc[r] = make_float4(blo.x, blo.y, bhi.x, bhi.y);
            }
#pragma unroll
            for (int r = 0; r < 4; r++)
#pragma unroll
                for (int cc = 0; cc < 4; cc++)
                    acc[r][cc] += ar[r].x * bc[cc].x + ar[r].y * bc[cc].y
                                + ar[r].z * bc[cc].z + ar[r].w * bc[cc].w;
        }
        if (c < 15) {
            __syncthreads();                // read->overwrite ordering (1 wave: cheap)
            const int nxt = cur ^ 1;
#pragma unroll
            for (int p = 0; p < 4; p++) {
                *(float2*)&As[nxt][srow + 8 * p][scol]     = make_float2(a_reg[p].x, a_reg[p].y);
                *(float2*)&As[nxt][srow + 8 * p][scol + 2] = make_float2(a_reg[p].z, a_reg[p].w);
                *(float2*)&Bs[nxt][srow + 8 * p][scol]     = make_float2(b_reg[p].x, b_reg[p].y);
                *(float2*)&Bs[nxt][srow + 8 * p][scol + 2] = make_float2(b_reg[p].z, b_reg[p].w);
            }
        }
    }

#pragma unroll
    for (int r = 0; r < 4; r++) {
        float4 v = make_float4(acc[r][0], acc[r][1], acc[r][2], acc[r][3]);
        *(float4*)&S[(i0 + 4 * ty + r) * NN + j0 + 4 * tx] = v;
    }
}

// ---------------- Kernel 2: per-anchor SmoothAP row + fused global reduce -----
__global__ __launch_bounds__(256) void sap_rows(const float* __restrict__ S,
                                               const int* __restrict__ labels,
                                               float* __restrict__ g_acc,
                                               unsigned int* __restrict__ g_cnt,
                                               float* __restrict__ out) {
    __shared__ float srow[NN];
    __shared__ float posf[NN];
    __shared__ int   poslist[NN];
    __shared__ int   npos_cnt;
    __shared__ float wave_part[4];

    const int i = blockIdx.x;
    const int t = threadIdx.x;
    if (t == 0) npos_cnt = 0;
    __syncthreads();

    const int li = labels[i];
    for (int k = t; k < NN; k += 256) {
        srow[k] = S[i * NN + k];
        bool p  = (labels[k] == li) && (k != i);
        posf[k] = p ? 1.f : 0.f;
        if (p) {
            int idx = atomicAdd(&npos_cnt, 1);
            poslist[idx] = k;
        }
    }
    __syncthreads();

    const int cnt  = npos_cnt;             // positives excluding self
    const int wave = t >> 6, lane = t & 63;
    // sigmoid(clip(x/T,-50,50)) = 1/(1+exp2(clip(-x*100*log2e, +-50*log2e)))
    const float C1   = 100.0f * 1.44269504088896340736f;
    const float CLIP = 50.0f * 1.44269504088896340736f;

    float acc = 0.f;
    if (cnt > 0) {
        for (int idx = wave; idx <= cnt; idx += 4) {  // idx==cnt -> eye term j==i
            const int   j   = (idx == cnt) ? i : poslist[idx];
            const float sij = srow[j];
            float sum_all = 0.f, sum_pos = 0.f;
#pragma unroll
            for (int kk = 0; kk < 8; kk++) {
                const int k = lane + (kk << 6);
                float y = (sij - srow[k]) * C1;
                y = fminf(fmaxf(y, -CLIP), CLIP);
                float tt = 1.0f / (1.0f + exp2f(y));
                if (k == j) tt = 0.f;                 // (1-eye)[j,k]
                sum_all += tt;
                sum_pos += tt * posf[k];              // posf[i]==0 excludes k==i
            }
#pragma unroll
            for (int off = 32; off; off >>= 1) {
                sum_all += __shfl_down(sum_all, off);
                sum_pos += __shfl_down(sum_pos, off);
            }
            if (lane == 0) {
                const float den = 1.0f + sum_all;
                const float num = (j == i) ? 1.0f : (1.0f + sum_pos);
                acc += num / den;
            }
        }
    }
    if (lane == 0) wave_part[wave] = acc;
    __syncthreads();
    if (t == 0) {
        float block_val = 0.f;
        if (cnt > 0) {
            float tot = wave_part[0] + wave_part[1] + wave_part[2] + wave_part[3];
            block_val = tot / (float)(cnt + 1);
        }
        atomicAdd(g_acc, block_val);
        __threadfence();
        unsigned int done = atomicAdd(g_cnt, 1u);
        if (done == NN - 1) {                  // last block finishes the reduce
            float total = atomicAdd(g_acc, 0.0f);
            out[0] = 1.0f - total / (float)NN;
        }
    }
}

extern "C" void kernel_launch(void* const* d_in, const int* in_sizes, int n_in,
                              void* d_out, int out_size, void* d_ws, size_t ws_size,
                              hipStream_t stream) {
    const float* preds  = (const float*)d_in[0];
    const int*   labels = (const int*)d_in[1];
    float* out = (float*)d_out;

    float*        S     = (float*)d_ws;                 // 512*512 floats = 1 MB
    float*        g_acc = (float*)d_ws + NN * NN;       // 1 float
    unsigned int* g_cnt = (unsigned int*)((float*)d_ws + NN * NN + 1);

    dim3 ggrid(NN / 32, NN / 32);
    sap_gemm<<<ggrid, 64, 0, stream>>>(preds, S, g_acc, g_cnt);
    sap_rows<<<NN, 256, 0, stream>>>(S, labels, g_acc, g_cnt, out);
}

// Round 4
// 80.437 us; speedup vs baseline: 1.1957x; 1.1957x over previous
//
#include <hip/hip_runtime.h>
#include <hip/hip_bf16.h>

#define NN 512

// ---------------- Kernel 1: split-K GEMM, S_part[kz] = P[:,kz*128:+128] @ P^T --
// 64x64 tile, 256 threads (4 waves), 4x4 micro, whole 64x128 slab staged once
// (64KB LDS, ONE barrier), XOR-swizzled float4 layout -> conflict-free b128.
__global__ __launch_bounds__(256) void sap_gemm(const float* __restrict__ P,
                                                float* __restrict__ Sp,   // 4 partials
                                                float* __restrict__ g_acc,
                                                unsigned int* __restrict__ g_cnt) {
    __shared__ float4 As4[64 * 32];   // [row][col4], col4 swizzled
    __shared__ float4 Bs4[64 * 32];
    const int t  = threadIdx.x;
    const int i0 = blockIdx.y * 64, j0 = blockIdx.x * 64;
    const int kz = blockIdx.z, kbase = kz * 128;

    if (i0 == 0 && j0 == 0 && kz == 0 && t == 0) { *g_acc = 0.f; *g_cnt = 0u; }

    // ---- stage 64x128 of A and B (8 float4 each per thread), swizzled ----
    {
        const int col4 = t & 31;        // float4 column 0..31
        const int row0 = t >> 5;        // 0..7
#pragma unroll
        for (int p = 0; p < 8; p++) {
            const int row = row0 + 8 * p;
            const float4 av = *(const float4*)&P[(i0 + row) * NN + kbase + col4 * 4];
            const float4 bv = *(const float4*)&P[(j0 + row) * NN + kbase + col4 * 4];
            const int c4s = (col4 & 24) | ((col4 & 7) ^ ((row >> 2) & 7));
            As4[row * 32 + c4s] = av;
            Bs4[row * 32 + c4s] = bv;
        }
    }
    __syncthreads();    // the only barrier

    const int tx = t & 15, ty = t >> 4;
    float acc[4][4] = {};

#pragma unroll 4
    for (int g = 0; g < 32; g++) {      // k-groups of 4
        const int ga = (g & 24) | ((g & 7) ^ (ty & 7));
        const int gb = (g & 24) | ((g & 7) ^ (tx & 7));
        float4 a[4], b[4];
#pragma unroll
        for (int r = 0; r < 4; r++) a[r] = As4[(4 * ty + r) * 32 + ga];
#pragma unroll
        for (int c = 0; c < 4; c++) b[c] = Bs4[(4 * tx + c) * 32 + gb];
#pragma unroll
        for (int r = 0; r < 4; r++)
#pragma unroll
            for (int c = 0; c < 4; c++)
                acc[r][c] += a[r].x * b[c].x + a[r].y * b[c].y
                           + a[r].z * b[c].z + a[r].w * b[c].w;
    }

    float* Sk = Sp + kz * NN * NN;
#pragma unroll
    for (int r = 0; r < 4; r++) {
        float4 v = make_float4(acc[r][0], acc[r][1], acc[r][2], acc[r][3]);
        *(float4*)&Sk[(i0 + 4 * ty + r) * NN + j0 + 4 * tx] = v;
    }
}

// ---------------- Kernel 2: per-anchor SmoothAP row + fused global reduce -----
__global__ __launch_bounds__(256) void sap_rows(const float* __restrict__ Sp,
                                               const int* __restrict__ labels,
                                               float* __restrict__ g_acc,
                                               unsigned int* __restrict__ g_cnt,
                                               float* __restrict__ out) {
    __shared__ float srow[NN];
    __shared__ float posf[NN];
    __shared__ int   poslist[NN];
    __shared__ int   npos_cnt;
    __shared__ float wave_part[4];

    const int i = blockIdx.x;
    const int t = threadIdx.x;
    if (t == 0) npos_cnt = 0;
    __syncthreads();

    const int li = labels[i];
    for (int k = t; k < NN; k += 256) {
        const int base = i * NN + k;
        float v = Sp[base] + Sp[NN * NN + base] + Sp[2 * NN * NN + base] + Sp[3 * NN * NN + base];
        srow[k] = v;
        bool p  = (labels[k] == li) && (k != i);
        posf[k] = p ? 1.f : 0.f;
        if (p) {
            int idx = atomicAdd(&npos_cnt, 1);
            poslist[idx] = k;
        }
    }
    __syncthreads();

    const int cnt  = npos_cnt;             // positives excluding self
    const int wave = t >> 6, lane = t & 63;
    // sigmoid(clip(x/T,-50,50)) = 1/(1+exp2(clip(-x*100*log2e, +-50*log2e)))
    const float C1   = 100.0f * 1.44269504088896340736f;
    const float CLIP = 50.0f * 1.44269504088896340736f;

    float acc = 0.f;
    if (cnt > 0) {
        for (int idx = wave; idx <= cnt; idx += 4) {  // idx==cnt -> eye term j==i
            const int   j   = (idx == cnt) ? i : poslist[idx];
            const float sij = srow[j];
            float sum_all = 0.f, sum_pos = 0.f;
#pragma unroll
            for (int kk = 0; kk < 8; kk++) {
                const int k = lane + (kk << 6);
                float y = (sij - srow[k]) * C1;
                y = fminf(fmaxf(y, -CLIP), CLIP);
                float tt = __builtin_amdgcn_rcpf(1.0f + __builtin_amdgcn_exp2f(y));
                if (k == j) tt = 0.f;                 // (1-eye)[j,k]
                sum_all += tt;
                sum_pos += tt * posf[k];              // posf[i]==0 excludes k==i
            }
#pragma unroll
            for (int off = 32; off; off >>= 1) {
                sum_all += __shfl_down(sum_all, off);
                sum_pos += __shfl_down(sum_pos, off);
            }
            if (lane == 0) {
                const float den = 1.0f + sum_all;
                const float num = (j == i) ? 1.0f : (1.0f + sum_pos);
                acc += num / den;
            }
        }
    }
    if (lane == 0) wave_part[wave] = acc;
    __syncthreads();
    if (t == 0) {
        float block_val = 0.f;
        if (cnt > 0) {
            float tot = wave_part[0] + wave_part[1] + wave_part[2] + wave_part[3];
            block_val = tot / (float)(cnt + 1);
        }
        atomicAdd(g_acc, block_val);
        __threadfence();
        unsigned int done = atomicAdd(g_cnt, 1u);
        if (done == NN - 1) {                  // last block finishes the reduce
            float total = atomicAdd(g_acc, 0.0f);
            out[0] = 1.0f - total / (float)NN;
        }
    }
}

extern "C" void kernel_launch(void* const* d_in, const int* in_sizes, int n_in,
                              void* d_out, int out_size, void* d_ws, size_t ws_size,
                              hipStream_t stream) {
    const float* preds  = (const float*)d_in[0];
    const int*   labels = (const int*)d_in[1];
    float* out = (float*)d_out;

    float*        Sp    = (float*)d_ws;                     // 4 x 512x512 floats = 4 MB
    float*        g_acc = (float*)d_ws + 4 * NN * NN;       // 1 float
    unsigned int* g_cnt = (unsigned int*)((float*)d_ws + 4 * NN * NN + 1);

    dim3 ggrid(NN / 64, NN / 64, 4);   // 8 x 8 x 4 = 256 blocks, 1 per CU
    sap_gemm<<<ggrid, 256, 0, stream>>>(preds, Sp, g_acc, g_cnt);
    sap_rows<<<NN, 256, 0, stream>>>(Sp, labels, g_acc, g_cnt, out);
}